// Round 1
// baseline (174.630 us; speedup 1.0000x reference)
//
#include <hip/hip_runtime.h>

#define NPTS 4096
#define NBATCH 16
#define THREADS 256

// Chamfer distance, fp32, B=16, N=M=4096, d=3.
// grid = (NPTS/THREADS, NBATCH, 2 directions) = 512 blocks -> 2 blocks/CU.
// Each block stages the full target point set (64 KB float4-padded) in LDS;
// each thread owns one query point and scans all 4096 targets.
// min over sqrt == sqrt over min (monotone), so one sqrt per point.
__global__ __launch_bounds__(THREADS) void chamfer_kernel(
    const float* __restrict__ shape, const float* __restrict__ tmpl,
    float* __restrict__ out) {
  __shared__ float4 tile[NPTS];  // 64 KB; reused as reduction scratch at the end

  const int b = blockIdx.y;
  const int dir = blockIdx.z;
  const float* Pb = (dir == 0 ? shape : tmpl) + (size_t)b * NPTS * 3;
  const float* Tb = (dir == 0 ? tmpl : shape) + (size_t)b * NPTS * 3;

  // Stage targets: packed float3 in global -> float4-padded LDS (ds_read_b128 later).
  for (int i = threadIdx.x; i < NPTS; i += THREADS) {
    tile[i] = make_float4(Tb[3 * i + 0], Tb[3 * i + 1], Tb[3 * i + 2], 0.0f);
  }
  __syncthreads();

  const int m = blockIdx.x * THREADS + threadIdx.x;
  const float px = Pb[3 * m + 0];
  const float py = Pb[3 * m + 1];
  const float pz = Pb[3 * m + 2];

  // 4 independent accumulators to break the v_min dependency chain.
  const float INF = 3.402823466e38f;
  float m0 = INF, m1 = INF, m2 = INF, m3 = INF;

  #pragma unroll 2
  for (int n = 0; n < NPTS; n += 4) {
    float4 t0 = tile[n + 0];
    float4 t1 = tile[n + 1];
    float4 t2 = tile[n + 2];
    float4 t3 = tile[n + 3];
    float dx, dy, dz, d2;
    dx = px - t0.x; dy = py - t0.y; dz = pz - t0.z;
    d2 = fmaf(dx, dx, fmaf(dy, dy, dz * dz));
    m0 = fminf(m0, d2);
    dx = px - t1.x; dy = py - t1.y; dz = pz - t1.z;
    d2 = fmaf(dx, dx, fmaf(dy, dy, dz * dz));
    m1 = fminf(m1, d2);
    dx = px - t2.x; dy = py - t2.y; dz = pz - t2.z;
    d2 = fmaf(dx, dx, fmaf(dy, dy, dz * dz));
    m2 = fminf(m2, d2);
    dx = px - t3.x; dy = py - t3.y; dz = pz - t3.z;
    d2 = fmaf(dx, dx, fmaf(dy, dy, dz * dz));
    m3 = fminf(m3, d2);
  }

  float md2 = fminf(fminf(m0, m1), fminf(m2, m3));
  float s = sqrtf(md2);

  // Wave (64-lane) shuffle reduction.
  #pragma unroll
  for (int off = 32; off > 0; off >>= 1) s += __shfl_down(s, off, 64);

  __syncthreads();  // all tile reads done; safe to reuse LDS
  float* red = (float*)tile;
  const int lane = threadIdx.x & 63;
  const int wid = threadIdx.x >> 6;
  if (lane == 0) red[wid] = s;
  __syncthreads();
  if (threadIdx.x == 0) {
    float tot = red[0] + red[1] + red[2] + red[3];
    // out = 0.01 * mean_over_16_batches(sum_p2t + sum_t2p)
    atomicAdd(out, tot * (0.01f / 16.0f));
  }
}

extern "C" void kernel_launch(void* const* d_in, const int* in_sizes, int n_in,
                              void* d_out, int out_size, void* d_ws, size_t ws_size,
                              hipStream_t stream) {
  const float* shape = (const float*)d_in[0];
  const float* tmpl = (const float*)d_in[1];
  float* out = (float*)d_out;

  // d_out is poisoned to 0xAA before every timed launch; atomics need zeros.
  hipMemsetAsync(out, 0, sizeof(float) * out_size, stream);

  dim3 grid(NPTS / THREADS, NBATCH, 2);
  chamfer_kernel<<<grid, dim3(THREADS), 0, stream>>>(shape, tmpl, out);
}

// Round 2
// 150.164 us; speedup vs baseline: 1.1629x; 1.1629x over previous
//
#include <hip/hip_runtime.h>

#define NPTS 4096
#define NBATCH 16
#define THREADS 256
#define Q 2  // queries per thread

// Chamfer distance, fp32, B=16, N=M=4096, d=3.
// grid = (4096/(256*Q)=8, 16, 2) = 256 blocks -> 1 block/CU.
// Block stages all 4096 targets in LDS as (x,y,z, 0.5*|t|^2).
// min_n |p-t|^2 = |p|^2 + 2*min_n(0.5|t|^2 - p.t)  -> 3 fma + 1 min per pair.
// Each thread owns Q=2 queries: one broadcast ds_read_b128 feeds 2x4 fma-chains.
__global__ __launch_bounds__(THREADS) void chamfer_kernel(
    const float* __restrict__ shape, const float* __restrict__ tmpl,
    float* __restrict__ out) {
  __shared__ float4 tile[NPTS];  // 64 KB

  const int b = blockIdx.y;
  const int dir = blockIdx.z;
  const float* Pb = (dir == 0 ? shape : tmpl) + (size_t)b * NPTS * 3;
  const float* Tb = (dir == 0 ? tmpl : shape) + (size_t)b * NPTS * 3;

  // Stage targets with float4 vector loads (3 float4 = 4 points), compute h=0.5|t|^2.
  const float4* T4 = (const float4*)Tb;
  for (int base = threadIdx.x * 4; base < NPTS; base += THREADS * 4) {
    const int k = base >> 2;  // group index
    float4 a = T4[3 * k + 0];
    float4 c = T4[3 * k + 1];
    float4 d = T4[3 * k + 2];
    // points: (a.x,a.y,a.z) (a.w,c.x,c.y) (c.z,c.w,d.x) (d.y,d.z,d.w)
    tile[base + 0] = make_float4(a.x, a.y, a.z,
                                 0.5f * fmaf(a.x, a.x, fmaf(a.y, a.y, a.z * a.z)));
    tile[base + 1] = make_float4(a.w, c.x, c.y,
                                 0.5f * fmaf(a.w, a.w, fmaf(c.x, c.x, c.y * c.y)));
    tile[base + 2] = make_float4(c.z, c.w, d.x,
                                 0.5f * fmaf(c.z, c.z, fmaf(c.w, c.w, d.x * d.x)));
    tile[base + 3] = make_float4(d.y, d.z, d.w,
                                 0.5f * fmaf(d.y, d.y, fmaf(d.z, d.z, d.w * d.w)));
  }
  __syncthreads();

  const int m0 = blockIdx.x * (THREADS * Q) + threadIdx.x;
  const int m1 = m0 + THREADS;
  const float qx0 = Pb[3 * m0 + 0], qy0 = Pb[3 * m0 + 1], qz0 = Pb[3 * m0 + 2];
  const float qx1 = Pb[3 * m1 + 0], qy1 = Pb[3 * m1 + 1], qz1 = Pb[3 * m1 + 2];
  const float nx0 = -qx0, ny0 = -qy0, nz0 = -qz0;
  const float nx1 = -qx1, ny1 = -qy1, nz1 = -qz1;
  const float p20 = fmaf(qx0, qx0, fmaf(qy0, qy0, qz0 * qz0));
  const float p21 = fmaf(qx1, qx1, fmaf(qy1, qy1, qz1 * qz1));

  const float INF = 3.402823466e38f;
  float a00 = INF, a01 = INF, a02 = INF, a03 = INF;  // query 0 accumulators
  float a10 = INF, a11 = INF, a12 = INF, a13 = INF;  // query 1 accumulators

  #pragma unroll 2
  for (int n = 0; n < NPTS; n += 4) {
    float4 t0 = tile[n + 0];
    float4 t1 = tile[n + 1];
    float4 t2 = tile[n + 2];
    float4 t3 = tile[n + 3];
    a00 = fminf(a00, fmaf(nx0, t0.x, fmaf(ny0, t0.y, fmaf(nz0, t0.z, t0.w))));
    a10 = fminf(a10, fmaf(nx1, t0.x, fmaf(ny1, t0.y, fmaf(nz1, t0.z, t0.w))));
    a01 = fminf(a01, fmaf(nx0, t1.x, fmaf(ny0, t1.y, fmaf(nz0, t1.z, t1.w))));
    a11 = fminf(a11, fmaf(nx1, t1.x, fmaf(ny1, t1.y, fmaf(nz1, t1.z, t1.w))));
    a02 = fminf(a02, fmaf(nx0, t2.x, fmaf(ny0, t2.y, fmaf(nz0, t2.z, t2.w))));
    a12 = fminf(a12, fmaf(nx1, t2.x, fmaf(ny1, t2.y, fmaf(nz1, t2.z, t2.w))));
    a03 = fminf(a03, fmaf(nx0, t3.x, fmaf(ny0, t3.y, fmaf(nz0, t3.z, t3.w))));
    a13 = fminf(a13, fmaf(nx1, t3.x, fmaf(ny1, t3.y, fmaf(nz1, t3.z, t3.w))));
  }

  const float v0 = fminf(fminf(a00, a01), fminf(a02, a03));
  const float v1 = fminf(fminf(a10, a11), fminf(a12, a13));
  const float d20 = fmaxf(fmaf(2.0f, v0, p20), 0.0f);
  const float d21 = fmaxf(fmaf(2.0f, v1, p21), 0.0f);
  float s = sqrtf(d20) + sqrtf(d21);

  // Wave (64-lane) shuffle reduction.
  #pragma unroll
  for (int off = 32; off > 0; off >>= 1) s += __shfl_down(s, off, 64);

  __syncthreads();  // all tile reads done; safe to reuse LDS
  float* red = (float*)tile;
  const int lane = threadIdx.x & 63;
  const int wid = threadIdx.x >> 6;
  if (lane == 0) red[wid] = s;
  __syncthreads();
  if (threadIdx.x == 0) {
    float tot = red[0] + red[1] + red[2] + red[3];
    // out = 0.01 * mean_over_16_batches(sum_p2t + sum_t2p)
    atomicAdd(out, tot * (0.01f / 16.0f));
  }
}

extern "C" void kernel_launch(void* const* d_in, const int* in_sizes, int n_in,
                              void* d_out, int out_size, void* d_ws, size_t ws_size,
                              hipStream_t stream) {
  const float* shape = (const float*)d_in[0];
  const float* tmpl = (const float*)d_in[1];
  float* out = (float*)d_out;

  // d_out is poisoned to 0xAA before every timed launch; atomics need zeros.
  hipMemsetAsync(out, 0, sizeof(float) * out_size, stream);

  dim3 grid(NPTS / (THREADS * Q), NBATCH, 2);
  chamfer_kernel<<<grid, dim3(THREADS), 0, stream>>>(shape, tmpl, out);
}

// Round 3
// 131.326 us; speedup vs baseline: 1.3297x; 1.1434x over previous
//
#include <hip/hip_runtime.h>

#define NPTS 4096
#define NBATCH 16
#define THREADS 256
#define QP 16            // queries per thread (kernel A)
#define TC 8             // target chunks (blocks) per (batch,dir)
#define TPC (NPTS / TC)  // 512 targets per chunk

// Chamfer, fp32, B=16, N=M=4096, d=3. Two-phase:
//  A: grid (TC, 16, 2) = 256 blocks. Block stages 512 targets (8 KB LDS) as
//     (x,y,z,0.5|t|^2); each thread owns 16 queries -> 64 VALU ops per
//     broadcast ds_read_b128 (LDS pipe now ~37% loaded vs VALU 100%).
//     Writes per-(query,tc) partial min of (0.5|t|^2 - p.t) to ws.
//  B: 512 blocks; min over tc, d2 = max(|p|^2 + 2*min, 0), sqrt, reduce.
// min_n |p-t|^2 = |p|^2 + 2*min_n(0.5|t|^2 - p.t): 3 fma + 1 min per pair.

__global__ __launch_bounds__(THREADS) void chamfer_partial(
    const float* __restrict__ shape, const float* __restrict__ tmpl,
    float* __restrict__ ws) {
  __shared__ float4 tile[TPC];  // 8 KB

  const int tc = blockIdx.x;
  const int b = blockIdx.y;
  const int dir = blockIdx.z;
  const float* Pb = (dir == 0 ? shape : tmpl) + (size_t)b * NPTS * 3;
  const float* Tb = (dir == 0 ? tmpl : shape) + (size_t)b * NPTS * 3;

  // Stage this chunk's 512 targets: 3 float4 global loads -> 4 padded pts + h.
  const float4* T4 = (const float4*)Tb;
  for (int g = threadIdx.x; g < TPC / 4; g += THREADS) {
    float4 a = T4[(tc * (TPC / 4) + g) * 3 + 0];
    float4 c = T4[(tc * (TPC / 4) + g) * 3 + 1];
    float4 d = T4[(tc * (TPC / 4) + g) * 3 + 2];
    const int base = g * 4;
    tile[base + 0] = make_float4(a.x, a.y, a.z,
                                 0.5f * fmaf(a.x, a.x, fmaf(a.y, a.y, a.z * a.z)));
    tile[base + 1] = make_float4(a.w, c.x, c.y,
                                 0.5f * fmaf(a.w, a.w, fmaf(c.x, c.x, c.y * c.y)));
    tile[base + 2] = make_float4(c.z, c.w, d.x,
                                 0.5f * fmaf(c.z, c.z, fmaf(c.w, c.w, d.x * d.x)));
    tile[base + 3] = make_float4(d.y, d.z, d.w,
                                 0.5f * fmaf(d.y, d.y, fmaf(d.z, d.z, d.w * d.w)));
  }
  __syncthreads();

  // Load 16 queries (negated components; |p|^2 handled in kernel B).
  float nx[QP], ny[QP], nz[QP], acc[QP];
  #pragma unroll
  for (int c = 0; c < QP; ++c) {
    const int mq = c * THREADS + threadIdx.x;
    nx[c] = -Pb[3 * mq + 0];
    ny[c] = -Pb[3 * mq + 1];
    nz[c] = -Pb[3 * mq + 2];
    acc[c] = 3.402823466e38f;
  }

  #pragma unroll 2
  for (int n = 0; n < TPC; n += 2) {
    float4 t0 = tile[n + 0];
    float4 t1 = tile[n + 1];
    #pragma unroll
    for (int c = 0; c < QP; ++c)
      acc[c] = fminf(acc[c], fmaf(nx[c], t0.x, fmaf(ny[c], t0.y, fmaf(nz[c], t0.z, t0.w))));
    #pragma unroll
    for (int c = 0; c < QP; ++c)
      acc[c] = fminf(acc[c], fmaf(nx[c], t1.x, fmaf(ny[c], t1.y, fmaf(nz[c], t1.z, t1.w))));
  }

  // ws layout [b][dir][tc][q]: coalesced writes here, coalesced reads in B.
  const int base = ((b * 2 + dir) * TC + tc) << 12;
  #pragma unroll
  for (int c = 0; c < QP; ++c)
    ws[base + c * THREADS + threadIdx.x] = acc[c];
}

__global__ __launch_bounds__(THREADS) void chamfer_combine(
    const float* __restrict__ shape, const float* __restrict__ tmpl,
    const float* __restrict__ ws, float* __restrict__ out) {
  __shared__ float red[4];
  const int g = blockIdx.x * THREADS + threadIdx.x;  // 0..131071
  const int b = g >> 13;
  const int rem = g & 8191;
  const int dir = rem >> 12;
  const int q = rem & 4095;

  const int base = ((b * 2 + dir) * TC) << 12;
  float m = 3.402823466e38f;
  #pragma unroll
  for (int tc = 0; tc < TC; ++tc) m = fminf(m, ws[base + (tc << 12) + q]);

  const float* Pb = (dir == 0 ? shape : tmpl) + (size_t)b * NPTS * 3;
  const float px = Pb[3 * q + 0], py = Pb[3 * q + 1], pz = Pb[3 * q + 2];
  const float p2 = fmaf(px, px, fmaf(py, py, pz * pz));
  const float d2 = fmaxf(fmaf(2.0f, m, p2), 0.0f);
  float s = sqrtf(d2);

  #pragma unroll
  for (int off = 32; off > 0; off >>= 1) s += __shfl_down(s, off, 64);
  const int lane = threadIdx.x & 63;
  const int wid = threadIdx.x >> 6;
  if (lane == 0) red[wid] = s;
  __syncthreads();
  if (threadIdx.x == 0)
    atomicAdd(out, (red[0] + red[1] + red[2] + red[3]) * (0.01f / 16.0f));
}

// ---- Fallback (round-2 single kernel) if ws is too small ----
__global__ __launch_bounds__(THREADS) void chamfer_fallback(
    const float* __restrict__ shape, const float* __restrict__ tmpl,
    float* __restrict__ out) {
  __shared__ float4 tile[NPTS];
  const int b = blockIdx.y;
  const int dir = blockIdx.z;
  const float* Pb = (dir == 0 ? shape : tmpl) + (size_t)b * NPTS * 3;
  const float* Tb = (dir == 0 ? tmpl : shape) + (size_t)b * NPTS * 3;
  const float4* T4 = (const float4*)Tb;
  for (int base = threadIdx.x * 4; base < NPTS; base += THREADS * 4) {
    const int k = base >> 2;
    float4 a = T4[3 * k + 0], c = T4[3 * k + 1], d = T4[3 * k + 2];
    tile[base + 0] = make_float4(a.x, a.y, a.z, 0.5f * fmaf(a.x, a.x, fmaf(a.y, a.y, a.z * a.z)));
    tile[base + 1] = make_float4(a.w, c.x, c.y, 0.5f * fmaf(a.w, a.w, fmaf(c.x, c.x, c.y * c.y)));
    tile[base + 2] = make_float4(c.z, c.w, d.x, 0.5f * fmaf(c.z, c.z, fmaf(c.w, c.w, d.x * d.x)));
    tile[base + 3] = make_float4(d.y, d.z, d.w, 0.5f * fmaf(d.y, d.y, fmaf(d.z, d.z, d.w * d.w)));
  }
  __syncthreads();
  const int m0 = blockIdx.x * (THREADS * 2) + threadIdx.x;
  const int m1 = m0 + THREADS;
  const float qx0 = Pb[3 * m0], qy0 = Pb[3 * m0 + 1], qz0 = Pb[3 * m0 + 2];
  const float qx1 = Pb[3 * m1], qy1 = Pb[3 * m1 + 1], qz1 = Pb[3 * m1 + 2];
  const float nx0 = -qx0, ny0 = -qy0, nz0 = -qz0;
  const float nx1 = -qx1, ny1 = -qy1, nz1 = -qz1;
  const float p20 = fmaf(qx0, qx0, fmaf(qy0, qy0, qz0 * qz0));
  const float p21 = fmaf(qx1, qx1, fmaf(qy1, qy1, qz1 * qz1));
  const float INF = 3.402823466e38f;
  float a00 = INF, a01 = INF, a10 = INF, a11 = INF;
  #pragma unroll 2
  for (int n = 0; n < NPTS; n += 2) {
    float4 t0 = tile[n], t1 = tile[n + 1];
    a00 = fminf(a00, fmaf(nx0, t0.x, fmaf(ny0, t0.y, fmaf(nz0, t0.z, t0.w))));
    a10 = fminf(a10, fmaf(nx1, t0.x, fmaf(ny1, t0.y, fmaf(nz1, t0.z, t0.w))));
    a01 = fminf(a01, fmaf(nx0, t1.x, fmaf(ny0, t1.y, fmaf(nz0, t1.z, t1.w))));
    a11 = fminf(a11, fmaf(nx1, t1.x, fmaf(ny1, t1.y, fmaf(nz1, t1.z, t1.w))));
  }
  float s = sqrtf(fmaxf(fmaf(2.0f, fminf(a00, a01), p20), 0.0f)) +
            sqrtf(fmaxf(fmaf(2.0f, fminf(a10, a11), p21), 0.0f));
  #pragma unroll
  for (int off = 32; off > 0; off >>= 1) s += __shfl_down(s, off, 64);
  __syncthreads();
  float* red = (float*)tile;
  if ((threadIdx.x & 63) == 0) red[threadIdx.x >> 6] = s;
  __syncthreads();
  if (threadIdx.x == 0)
    atomicAdd(out, (red[0] + red[1] + red[2] + red[3]) * (0.01f / 16.0f));
}

extern "C" void kernel_launch(void* const* d_in, const int* in_sizes, int n_in,
                              void* d_out, int out_size, void* d_ws, size_t ws_size,
                              hipStream_t stream) {
  const float* shape = (const float*)d_in[0];
  const float* tmpl = (const float*)d_in[1];
  float* out = (float*)d_out;

  hipMemsetAsync(out, 0, sizeof(float) * out_size, stream);

  const size_t ws_needed = (size_t)NBATCH * 2 * TC * NPTS * sizeof(float);  // 4 MB
  if (ws_size >= ws_needed) {
    dim3 gridA(TC, NBATCH, 2);
    chamfer_partial<<<gridA, dim3(THREADS), 0, stream>>>(shape, tmpl, (float*)d_ws);
    const int nq = NBATCH * 2 * NPTS;  // 131072
    chamfer_combine<<<dim3(nq / THREADS), dim3(THREADS), 0, stream>>>(
        shape, tmpl, (const float*)d_ws, out);
  } else {
    dim3 grid(NPTS / (THREADS * 2), NBATCH, 2);
    chamfer_fallback<<<grid, dim3(THREADS), 0, stream>>>(shape, tmpl, out);
  }
}

// Round 4
// 109.254 us; speedup vs baseline: 1.5984x; 1.2020x over previous
//
#include <hip/hip_runtime.h>

#define NPTS 4096
#define NBATCH 16
#define THREADS 256
#define QP 16            // queries per thread (kernel A)
#define TC 16            // target chunks (blocks) per (batch,dir)
#define TPC (NPTS / TC)  // 256 targets per chunk

// Chamfer, fp32, B=16, N=M=4096, d=3. Two-phase:
//  A: grid (TC, 16, 2) = 512 blocks -> 2 blocks/CU, 2 waves/SIMD (latency hiding).
//     Block stages TPC targets (4 KB LDS) as (x,y,z,0.5|t|^2); each thread owns
//     16 queries -> 64 VALU ops per broadcast ds_read_b128.
//     __launch_bounds__(256,2): 256-VGPR budget so the 64-reg query set stays
//     in registers (round 3's 48-VGPR clamp spilled it: 75us @ 63% busy).
//     Writes per-(query,tc) partial min of (0.5|t|^2 - p.t) to ws (8 MB).
//  B: 512 blocks; min over tc, d2 = max(|p|^2 + 2*min, 0), sqrt, reduce.
// min_n |p-t|^2 = |p|^2 + 2*min_n(0.5|t|^2 - p.t): 3 fma + 1 min per pair.

__global__ __launch_bounds__(THREADS, 2) void chamfer_partial(
    const float* __restrict__ shape, const float* __restrict__ tmpl,
    float* __restrict__ ws) {
  __shared__ float4 tile[TPC];  // 4 KB

  const int tc = blockIdx.x;
  const int b = blockIdx.y;
  const int dir = blockIdx.z;
  const float* Pb = (dir == 0 ? shape : tmpl) + (size_t)b * NPTS * 3;
  const float* Tb = (dir == 0 ? tmpl : shape) + (size_t)b * NPTS * 3;

  // Stage this chunk's targets: 3 float4 global loads -> 4 padded pts + h.
  const float4* T4 = (const float4*)Tb;
  for (int g = threadIdx.x; g < TPC / 4; g += THREADS) {
    float4 a = T4[(tc * (TPC / 4) + g) * 3 + 0];
    float4 c = T4[(tc * (TPC / 4) + g) * 3 + 1];
    float4 d = T4[(tc * (TPC / 4) + g) * 3 + 2];
    const int base = g * 4;
    tile[base + 0] = make_float4(a.x, a.y, a.z,
                                 0.5f * fmaf(a.x, a.x, fmaf(a.y, a.y, a.z * a.z)));
    tile[base + 1] = make_float4(a.w, c.x, c.y,
                                 0.5f * fmaf(a.w, a.w, fmaf(c.x, c.x, c.y * c.y)));
    tile[base + 2] = make_float4(c.z, c.w, d.x,
                                 0.5f * fmaf(c.z, c.z, fmaf(c.w, c.w, d.x * d.x)));
    tile[base + 3] = make_float4(d.y, d.z, d.w,
                                 0.5f * fmaf(d.y, d.y, fmaf(d.z, d.z, d.w * d.w)));
  }
  __syncthreads();

  // Load 16 queries (negated components; |p|^2 handled in kernel B).
  float nx[QP], ny[QP], nz[QP], acc[QP];
  #pragma unroll
  for (int c = 0; c < QP; ++c) {
    const int mq = c * THREADS + threadIdx.x;
    nx[c] = -Pb[3 * mq + 0];
    ny[c] = -Pb[3 * mq + 1];
    nz[c] = -Pb[3 * mq + 2];
    acc[c] = 3.402823466e38f;
  }

  for (int n = 0; n < TPC; n += 4) {
    float4 t0 = tile[n + 0];
    float4 t1 = tile[n + 1];
    float4 t2 = tile[n + 2];
    float4 t3 = tile[n + 3];
    #pragma unroll
    for (int c = 0; c < QP; ++c)
      acc[c] = fminf(acc[c], fmaf(nx[c], t0.x, fmaf(ny[c], t0.y, fmaf(nz[c], t0.z, t0.w))));
    #pragma unroll
    for (int c = 0; c < QP; ++c)
      acc[c] = fminf(acc[c], fmaf(nx[c], t1.x, fmaf(ny[c], t1.y, fmaf(nz[c], t1.z, t1.w))));
    #pragma unroll
    for (int c = 0; c < QP; ++c)
      acc[c] = fminf(acc[c], fmaf(nx[c], t2.x, fmaf(ny[c], t2.y, fmaf(nz[c], t2.z, t2.w))));
    #pragma unroll
    for (int c = 0; c < QP; ++c)
      acc[c] = fminf(acc[c], fmaf(nx[c], t3.x, fmaf(ny[c], t3.y, fmaf(nz[c], t3.z, t3.w))));
  }

  // ws layout [b][dir][tc][q]: coalesced writes here, coalesced reads in B.
  const int base = ((b * 2 + dir) * TC + tc) << 12;
  #pragma unroll
  for (int c = 0; c < QP; ++c)
    ws[base + c * THREADS + threadIdx.x] = acc[c];
}

__global__ __launch_bounds__(THREADS) void chamfer_combine(
    const float* __restrict__ shape, const float* __restrict__ tmpl,
    const float* __restrict__ ws, float* __restrict__ out) {
  __shared__ float red[4];
  const int g = blockIdx.x * THREADS + threadIdx.x;  // 0..131071
  const int b = g >> 13;
  const int rem = g & 8191;
  const int dir = rem >> 12;
  const int q = rem & 4095;

  const int base = ((b * 2 + dir) * TC) << 12;
  float m = 3.402823466e38f;
  #pragma unroll
  for (int tc = 0; tc < TC; ++tc) m = fminf(m, ws[base + (tc << 12) + q]);

  const float* Pb = (dir == 0 ? shape : tmpl) + (size_t)b * NPTS * 3;
  const float px = Pb[3 * q + 0], py = Pb[3 * q + 1], pz = Pb[3 * q + 2];
  const float p2 = fmaf(px, px, fmaf(py, py, pz * pz));
  const float d2 = fmaxf(fmaf(2.0f, m, p2), 0.0f);
  float s = sqrtf(d2);

  #pragma unroll
  for (int off = 32; off > 0; off >>= 1) s += __shfl_down(s, off, 64);
  const int lane = threadIdx.x & 63;
  const int wid = threadIdx.x >> 6;
  if (lane == 0) red[wid] = s;
  __syncthreads();
  if (threadIdx.x == 0)
    atomicAdd(out, (red[0] + red[1] + red[2] + red[3]) * (0.01f / 16.0f));
}

// ---- Fallback (round-2 single kernel) if ws is too small ----
__global__ __launch_bounds__(THREADS) void chamfer_fallback(
    const float* __restrict__ shape, const float* __restrict__ tmpl,
    float* __restrict__ out) {
  __shared__ float4 tile[NPTS];
  const int b = blockIdx.y;
  const int dir = blockIdx.z;
  const float* Pb = (dir == 0 ? shape : tmpl) + (size_t)b * NPTS * 3;
  const float* Tb = (dir == 0 ? tmpl : shape) + (size_t)b * NPTS * 3;
  const float4* T4 = (const float4*)Tb;
  for (int base = threadIdx.x * 4; base < NPTS; base += THREADS * 4) {
    const int k = base >> 2;
    float4 a = T4[3 * k + 0], c = T4[3 * k + 1], d = T4[3 * k + 2];
    tile[base + 0] = make_float4(a.x, a.y, a.z, 0.5f * fmaf(a.x, a.x, fmaf(a.y, a.y, a.z * a.z)));
    tile[base + 1] = make_float4(a.w, c.x, c.y, 0.5f * fmaf(a.w, a.w, fmaf(c.x, c.x, c.y * c.y)));
    tile[base + 2] = make_float4(c.z, c.w, d.x, 0.5f * fmaf(c.z, c.z, fmaf(c.w, c.w, d.x * d.x)));
    tile[base + 3] = make_float4(d.y, d.z, d.w, 0.5f * fmaf(d.y, d.y, fmaf(d.z, d.z, d.w * d.w)));
  }
  __syncthreads();
  const int m0 = blockIdx.x * (THREADS * 2) + threadIdx.x;
  const int m1 = m0 + THREADS;
  const float qx0 = Pb[3 * m0], qy0 = Pb[3 * m0 + 1], qz0 = Pb[3 * m0 + 2];
  const float qx1 = Pb[3 * m1], qy1 = Pb[3 * m1 + 1], qz1 = Pb[3 * m1 + 2];
  const float nx0 = -qx0, ny0 = -qy0, nz0 = -qz0;
  const float nx1 = -qx1, ny1 = -qy1, nz1 = -qz1;
  const float p20 = fmaf(qx0, qx0, fmaf(qy0, qy0, qz0 * qz0));
  const float p21 = fmaf(qx1, qx1, fmaf(qy1, qy1, qz1 * qz1));
  const float INF = 3.402823466e38f;
  float a00 = INF, a01 = INF, a10 = INF, a11 = INF;
  #pragma unroll 2
  for (int n = 0; n < NPTS; n += 2) {
    float4 t0 = tile[n], t1 = tile[n + 1];
    a00 = fminf(a00, fmaf(nx0, t0.x, fmaf(ny0, t0.y, fmaf(nz0, t0.z, t0.w))));
    a10 = fminf(a10, fmaf(nx1, t0.x, fmaf(ny1, t0.y, fmaf(nz1, t0.z, t0.w))));
    a01 = fminf(a01, fmaf(nx0, t1.x, fmaf(ny0, t1.y, fmaf(nz0, t1.z, t1.w))));
    a11 = fminf(a11, fmaf(nx1, t1.x, fmaf(ny1, t1.y, fmaf(nz1, t1.z, t1.w))));
  }
  float s = sqrtf(fmaxf(fmaf(2.0f, fminf(a00, a01), p20), 0.0f)) +
            sqrtf(fmaxf(fmaf(2.0f, fminf(a10, a11), p21), 0.0f));
  #pragma unroll
  for (int off = 32; off > 0; off >>= 1) s += __shfl_down(s, off, 64);
  __syncthreads();
  float* red = (float*)tile;
  if ((threadIdx.x & 63) == 0) red[threadIdx.x >> 6] = s;
  __syncthreads();
  if (threadIdx.x == 0)
    atomicAdd(out, (red[0] + red[1] + red[2] + red[3]) * (0.01f / 16.0f));
}

extern "C" void kernel_launch(void* const* d_in, const int* in_sizes, int n_in,
                              void* d_out, int out_size, void* d_ws, size_t ws_size,
                              hipStream_t stream) {
  const float* shape = (const float*)d_in[0];
  const float* tmpl = (const float*)d_in[1];
  float* out = (float*)d_out;

  hipMemsetAsync(out, 0, sizeof(float) * out_size, stream);

  const size_t ws_needed = (size_t)NBATCH * 2 * TC * NPTS * sizeof(float);  // 8 MB
  if (ws_size >= ws_needed) {
    dim3 gridA(TC, NBATCH, 2);
    chamfer_partial<<<gridA, dim3(THREADS), 0, stream>>>(shape, tmpl, (float*)d_ws);
    const int nq = NBATCH * 2 * NPTS;  // 131072
    chamfer_combine<<<dim3(nq / THREADS), dim3(THREADS), 0, stream>>>(
        shape, tmpl, (const float*)d_ws, out);
  } else {
    dim3 grid(NPTS / (THREADS * 2), NBATCH, 2);
    chamfer_fallback<<<grid, dim3(THREADS), 0, stream>>>(shape, tmpl, out);
  }
}